// Round 4
// baseline (2863.833 us; speedup 1.0000x reference)
//
#include <hip/hip_runtime.h>

// Problem constants (fixed by reference).
constexpr int NNODES = 200000;
constexpr int NAUT   = 100000;
constexpr int NEDGE  = 600000;
constexpr int HIDC   = 128;
constexpr int OUTCH  = 64;
constexpr int RELS   = 4;
constexpr int SCAN_N = RELS * NNODES;  // 800000 bins
constexpr int LDA    = HIDC + 4;       // LDS pad: breaks row-aligned bank conflicts

// ---------------- prep kernels ----------------

// W[r][i][o] = sum_b comp[r][b] * basis[b][i][o]
__global__ void makew_kernel(const float* __restrict__ basis, const float* __restrict__ comp,
                             float* __restrict__ W, int io_sz) {
    int idx = blockIdx.x * 256 + threadIdx.x;
    if (idx >= RELS * io_sz) return;
    int r = idx / io_sz, io = idx % io_sz;
    float s = 0.f;
#pragma unroll
    for (int b = 0; b < 4; b++) s += comp[r * 4 + b] * basis[b * io_sz + io];
    W[idx] = s;
}

// int count per (relation, dst) bin
__global__ void count_kernel(const int* __restrict__ dst, const int* __restrict__ et,
                             int* __restrict__ bins) {
    int e = blockIdx.x * 256 + threadIdx.x;
    if (e < NEDGE) atomicAdd(&bins[et[e] * NNODES + dst[e]], 1);
}

// ---- 3-phase exclusive scan over 800k bins, in-place (counts -> starts) ----
__global__ void scan1_kernel(int* __restrict__ bins, int* __restrict__ blockSums) {
    __shared__ int s[256];
    int b = blockIdx.x, t = threadIdx.x;
    int base = b * 1024 + t * 4;
    int v[4], sum = 0;
#pragma unroll
    for (int i = 0; i < 4; i++) {
        v[i] = (base + i < SCAN_N) ? bins[base + i] : 0;
        sum += v[i];
    }
    s[t] = sum;
    __syncthreads();
    for (int off = 1; off < 256; off <<= 1) {
        int x = (t >= off) ? s[t - off] : 0;
        __syncthreads();
        if (t >= off) s[t] += x;
        __syncthreads();
    }
    int run = s[t] - sum;  // exclusive prefix of this thread's chunk
    if (t == 255) blockSums[b] = s[255];
#pragma unroll
    for (int i = 0; i < 4; i++) {
        if (base + i < SCAN_N) bins[base + i] = run;
        run += v[i];
    }
}

__global__ void scan2_kernel(int* __restrict__ blockSums, int nb) {
    __shared__ int s[256];
    int t = threadIdx.x;
    int carry = 0;
    for (int base = 0; base < nb; base += 256) {
        int v = (base + t < nb) ? blockSums[base + t] : 0;
        s[t] = v;
        __syncthreads();
        for (int off = 1; off < 256; off <<= 1) {
            int x = (t >= off) ? s[t - off] : 0;
            __syncthreads();
            if (t >= off) s[t] += x;
            __syncthreads();
        }
        if (base + t < nb) blockSums[base + t] = carry + (s[t] - v);
        int total = s[255];
        __syncthreads();
        carry += total;
    }
}

// add block carries; also produce the scatter-cursor copy
__global__ void scan3_kernel(int* __restrict__ bins, const int* __restrict__ blockSums,
                             int* __restrict__ binCur) {
    int i = blockIdx.x * 256 + threadIdx.x;
    if (i < SCAN_N) {
        int v = bins[i] + blockSums[i >> 10];
        bins[i] = v;
        binCur[i] = v;
    }
}

// scatter SRC ids into (relation,dst)-sorted order; binCur becomes end-offsets
__global__ void scatter_kernel(const int* __restrict__ src, const int* __restrict__ dst,
                               const int* __restrict__ et, int* __restrict__ binCur,
                               int* __restrict__ srcSorted) {
    int e = blockIdx.x * 256 + threadIdx.x;
    if (e < NEDGE) {
        int bin = et[e] * NNODES + dst[e];
        int pos = atomicAdd(&binCur[bin], 1);
        srcSorted[pos] = src[e];
    }
}

// ---------------- projection GEMM: C[M,128] = relu(A[M,K] @ B[K,128] + bias) ----
__global__ __launch_bounds__(256) void gemm_kernel(const float* __restrict__ A,
                                                   const float* __restrict__ B,
                                                   const float* __restrict__ bias,
                                                   float* __restrict__ C, int M, int K) {
    __shared__ float sA[64 * 128];
    int tid = threadIdx.x;
    int row0 = blockIdx.x * 64;

    for (int i = tid; i < (64 * K) >> 2; i += 256) {
        int off = i << 2;
        int rr = off / K, cc = off % K;
        int row = row0 + rr;
        float4 v = {0.f, 0.f, 0.f, 0.f};
        if (row < M) v = *(const float4*)(A + (long)row * K + cc);
        *(float4*)(sA + rr * K + cc) = v;
    }
    __syncthreads();

    int cg = tid & 31, rg = tid >> 5;
    int c0 = cg * 4, r0 = rg * 8;
    float acc[8][4];
#pragma unroll
    for (int i = 0; i < 8; i++)
#pragma unroll
        for (int j = 0; j < 4; j++) acc[i][j] = 0.f;

#pragma unroll 2
    for (int k = 0; k < K; k += 4) {
        float a[8][4];
#pragma unroll
        for (int i = 0; i < 8; i++)
            *(float4*)(a[i]) = *(const float4*)(sA + (r0 + i) * K + k);
#pragma unroll
        for (int j = 0; j < 4; j++) {
            float b[4];
            *(float4*)b = *(const float4*)(B + (k + j) * 128 + c0);
#pragma unroll
            for (int i = 0; i < 8; i++)
#pragma unroll
                for (int jj = 0; jj < 4; jj++)
                    acc[i][jj] = fmaf(a[i][j], b[jj], acc[i][jj]);
        }
    }

#pragma unroll
    for (int i = 0; i < 8; i++) {
        int row = row0 + r0 + i;
        if (row >= M) continue;
        float v[4];
#pragma unroll
        for (int jj = 0; jj < 4; jj++) v[jj] = fmaxf(acc[i][jj] + bias[c0 + jj], 0.f);
        *(float4*)(C + (long)row * 128 + c0) = *(float4*)v;
    }
}

// ---------------- fused dst-centric RGCN conv (NO atomics) ----------------
// Interleaved structure (the r0 600us skeleton -- specialization lost twice),
// but 512 threads on the same 64-row tile:
//   - gather: 8 threads/row (was 4). Wave spans 8 rows -> less trip-count
//     divergence; 2x outstanding loads per block.
//   - GEMM: thread tile 2 rows x 8 cols (acc=16 regs, est ~52-60 VGPR).
//   - LDS unchanged 33.8KB -> 4 blocks/CU x 8 waves = 32 waves/CU (100% cap,
//     was 16). More waves to hide gather latency + smaller barrier convoys
//     relative to resident work.
template <int NC, bool HASROOT, bool DORELU>
__global__ __launch_bounds__(512) void conv_kernel(const float* __restrict__ x,
                                                   const float* __restrict__ Wall,
                                                   const float* __restrict__ root,
                                                   const int* __restrict__ binStart,
                                                   const int* __restrict__ binEnd,
                                                   const int* __restrict__ srcSorted,
                                                   float* __restrict__ out) {
    constexpr int CPT = (NC == 128) ? 8 : 4;  // cols per thread
    constexpr int NF4 = CPT / 4;              // float4s per thread (2 or 1)
    __shared__ float sA[64 * LDA];
    int tid = threadIdx.x;
    int v0 = blockIdx.x * 64;

    const int grow = tid >> 3;  // gather: 8 threads per row (512/8 = 64 rows)
    const int gq = tid & 7;     // this thread's interleaved column slice
    const int cg = tid & 15, rg = tid >> 4;   // 16 col-groups, 32 row-groups
    const int c0 = cg * CPT, r0 = rg * 2;

    float acc[2][CPT];
#pragma unroll
    for (int i = 0; i < 2; i++)
#pragma unroll
        for (int j = 0; j < CPT; j++) acc[i][j] = 0.f;

    constexpr int NPHASE = HASROOT ? RELS + 1 : RELS;
#pragma unroll 1
    for (int ph = 0; ph < NPHASE; ph++) {
        if (ph > 0) __syncthreads();  // protect sA from previous phase's readers
        if (ph < RELS) {
            int bin = ph * NNODES + v0 + grow;
            int s = binStart[bin], e = binEnd[bin];
            float4 a4[4];
#pragma unroll
            for (int i = 0; i < 4; i++) a4[i] = make_float4(0.f, 0.f, 0.f, 0.f);
            for (int j = s; j < e; j++) {
                const float* xs = x + (long)srcSorted[j] * HIDC;
#pragma unroll
                for (int i = 0; i < 4; i++) {
                    float4 v = *(const float4*)(xs + (gq + i * 8) * 4);
                    a4[i].x += v.x; a4[i].y += v.y; a4[i].z += v.z; a4[i].w += v.w;
                }
            }
            float sc = 1.0f / (float)max(e - s, 1);
#pragma unroll
            for (int i = 0; i < 4; i++) {
                float4 w = a4[i];
                w.x *= sc; w.y *= sc; w.z *= sc; w.w *= sc;
                *(float4*)(sA + grow * LDA + (gq + i * 8) * 4) = w;
            }
        } else {
            // root phase: coalesced load of the block's own 64 x-rows
#pragma unroll
            for (int i = 0; i < 4; i++) {
                int i4 = tid + 512 * i;  // 2048 float4 = 64x128 floats
                int row = i4 >> 5, col4 = i4 & 31;
                *(float4*)(sA + row * LDA + col4 * 4) =
                    *(const float4*)(x + (long)(v0 + row) * HIDC + col4 * 4);
            }
        }
        __syncthreads();

        const float* __restrict__ B = (ph < RELS) ? (Wall + ph * HIDC * NC) : root;
#pragma unroll 2
        for (int k = 0; k < HIDC; k += 4) {
            float a[2][4];
#pragma unroll
            for (int i = 0; i < 2; i++)
                *(float4*)(a[i]) = *(const float4*)(sA + (r0 + i) * LDA + k);
#pragma unroll
            for (int j = 0; j < 4; j++) {
                float b[CPT];
#pragma unroll
                for (int f = 0; f < NF4; f++)
                    *(float4*)(b + f * 4) = *(const float4*)(B + (k + j) * NC + c0 + f * 4);
#pragma unroll
                for (int i = 0; i < 2; i++)
#pragma unroll
                    for (int jj = 0; jj < CPT; jj++)
                        acc[i][jj] = fmaf(a[i][j], b[jj], acc[i][jj]);
            }
        }
    }

    // epilogue: exactly one coalesced store per output element
#pragma unroll
    for (int i = 0; i < 2; i++) {
        int row = v0 + r0 + i;  // NNODES % 64 == 0: no guard needed
        float v[CPT];
#pragma unroll
        for (int jj = 0; jj < CPT; jj++)
            v[jj] = DORELU ? fmaxf(acc[i][jj], 0.f) : acc[i][jj];
#pragma unroll
        for (int f = 0; f < NF4; f++)
            *(float4*)(out + (long)row * NC + c0 + f * 4) = *(float4*)(v + f * 4);
    }
}

// ---------------- launch ----------------

extern "C" void kernel_launch(void* const* d_in, const int* in_sizes, int n_in,
                              void* d_out, int out_size, void* d_ws, size_t ws_size,
                              hipStream_t stream) {
    const float* xa     = (const float*)d_in[0];
    const float* xp     = (const float*)d_in[1];
    const int*   src    = (const int*)d_in[2];
    const int*   dst    = (const int*)d_in[3];
    const int*   et     = (const int*)d_in[4];
    const float* Wpa    = (const float*)d_in[5];
    const float* bpa    = (const float*)d_in[6];
    const float* Wpb    = (const float*)d_in[7];
    const float* bpb    = (const float*)d_in[8];
    const float* basis0 = (const float*)d_in[9];
    const float* comp0  = (const float*)d_in[10];
    const float* basis1 = (const float*)d_in[11];
    const float* comp1  = (const float*)d_in[12];
    const float* root1  = (const float*)d_in[13];
    const float* basis2 = (const float*)d_in[14];
    const float* comp2  = (const float*)d_in[15];
    const float* root2  = (const float*)d_in[16];

    // d_out layout: final [N,64] | x_lat0 [N,128] | x_lat1 [N,128] | x_lat2 [N,128]
    float* out_final = (float*)d_out;
    float* x0 = out_final + (size_t)NNODES * OUTCH;
    float* x1 = x0 + (size_t)NNODES * HIDC;
    float* x2 = x1 + (size_t)NNODES * HIDC;

    // workspace (~9.3 MB)
    float* W0      = (float*)d_ws;                      // 4*128*128
    float* W1      = W0 + RELS * HIDC * HIDC;           // 4*128*128
    float* W2      = W1 + RELS * HIDC * HIDC;           // 4*128*64
    int* bins      = (int*)(W2 + RELS * HIDC * OUTCH);  // 800000: counts -> starts
    int* binCur    = bins + SCAN_N;                     // 800000: cursor -> ends
    int* blockSums = binCur + SCAN_N;                   // 800
    int* srcSorted = blockSums + 800;                   // 600000

    dim3 b256(256);
    dim3 b512(512);
    int egrid = (NEDGE + 255) / 256;
    int nScanBlocks = (SCAN_N + 1023) / 1024;  // 782

    // ---- counting-sort of src ids by (relation, dst) ----
    hipMemsetAsync(bins, 0, (size_t)SCAN_N * sizeof(int), stream);
    hipLaunchKernelGGL(count_kernel, dim3(egrid), b256, 0, stream, dst, et, bins);
    hipLaunchKernelGGL(scan1_kernel, dim3(nScanBlocks), b256, 0, stream, bins, blockSums);
    hipLaunchKernelGGL(scan2_kernel, dim3(1), b256, 0, stream, blockSums, nScanBlocks);
    hipLaunchKernelGGL(scan3_kernel, dim3((SCAN_N + 255) / 256), b256, 0, stream,
                       bins, blockSums, binCur);
    hipLaunchKernelGGL(scatter_kernel, dim3(egrid), b256, 0, stream,
                       src, dst, et, binCur, srcSorted);

    // ---- materialize relation weights ----
    hipLaunchKernelGGL(makew_kernel, dim3((RELS * HIDC * HIDC + 255) / 256), b256, 0, stream,
                       basis0, comp0, W0, HIDC * HIDC);
    hipLaunchKernelGGL(makew_kernel, dim3((RELS * HIDC * HIDC + 255) / 256), b256, 0, stream,
                       basis1, comp1, W1, HIDC * HIDC);
    hipLaunchKernelGGL(makew_kernel, dim3((RELS * HIDC * OUTCH + 255) / 256), b256, 0, stream,
                       basis2, comp2, W2, HIDC * OUTCH);

    // ---- projections -> x_lat0 ----
    hipLaunchKernelGGL(gemm_kernel, dim3((NAUT + 63) / 64), b256, 0, stream,
                       xa, Wpa, bpa, x0, NAUT, 64);
    hipLaunchKernelGGL(gemm_kernel, dim3((NAUT + 63) / 64), b256, 0, stream,
                       xp, Wpb, bpb, x0 + (size_t)NAUT * HIDC, NAUT, 96);

    int cgrid = NNODES / 64;  // 3125, exact

    // conv0: x1 = relu(aggr(x0))            (no root)
    hipLaunchKernelGGL((conv_kernel<128, false, true>), dim3(cgrid), b512, 0, stream,
                       x0, W0, (const float*)nullptr, bins, binCur, srcSorted, x1);
    // conv1: x2 = relu(x1 @ root1 + aggr(x1))
    hipLaunchKernelGGL((conv_kernel<128, true, true>), dim3(cgrid), b512, 0, stream,
                       x1, W1, root1, bins, binCur, srcSorted, x2);
    // conv2: final = x2 @ root2 + aggr(x2)  (no relu)
    hipLaunchKernelGGL((conv_kernel<64, true, false>), dim3(cgrid), b512, 0, stream,
                       x2, W2, root2, bins, binCur, srcSorted, out_final);
}

// Round 5
// 979.496 us; speedup vs baseline: 2.9238x; 2.9238x over previous
//
#include <hip/hip_runtime.h>

// Problem constants (fixed by reference).
constexpr int NNODES = 200000;
constexpr int NAUT   = 100000;
constexpr int NEDGE  = 600000;
constexpr int HIDC   = 128;
constexpr int OUTCH  = 64;
constexpr int RELS   = 4;
constexpr int SCAN_N = RELS * NNODES;  // 800000 bins
constexpr int LDB    = HIDC + 8;       // bf16 LDS row stride (272B: keeps 16B align + spreads banks)

typedef __attribute__((ext_vector_type(8))) short bf16x8;
typedef __attribute__((ext_vector_type(4))) float f32x4;

// ---------------- bf16 split helpers ----------------
__device__ __forceinline__ unsigned short f2bf(float f) {
    unsigned int b = __float_as_uint(f);
    b += 0x7FFFu + ((b >> 16) & 1u);  // round-to-nearest-even
    return (unsigned short)(b >> 16);
}
__device__ __forceinline__ float bf2f(unsigned short u) {
    return __uint_as_float(((unsigned int)u) << 16);
}

// MFMA B/A fragment offset for element (k,n) of a [128 x N] matrix, NB = N/16.
// Layout: [kb][nb][lane][j] with lane = ((k>>3)&3)*16 + (n&15), j = k&7.
__device__ __forceinline__ int fragoff(int k, int n, int NB) {
    return ((k >> 5) * NB + (n >> 4)) * 512 + (((k >> 3) & 3) * 16 + (n & 15)) * 8 + (k & 7);
}

// ---------------- prep kernels ----------------

// int count per (relation, dst) bin
__global__ void count_kernel(const int* __restrict__ dst, const int* __restrict__ et,
                             int* __restrict__ bins) {
    int e = blockIdx.x * 256 + threadIdx.x;
    if (e < NEDGE) atomicAdd(&bins[et[e] * NNODES + dst[e]], 1);
}

// ---- 3-phase exclusive scan over 800k bins, in-place (counts -> starts) ----
__global__ void scan1_kernel(int* __restrict__ bins, int* __restrict__ blockSums) {
    __shared__ int s[256];
    int b = blockIdx.x, t = threadIdx.x;
    int base = b * 1024 + t * 4;
    int v[4], sum = 0;
#pragma unroll
    for (int i = 0; i < 4; i++) {
        v[i] = (base + i < SCAN_N) ? bins[base + i] : 0;
        sum += v[i];
    }
    s[t] = sum;
    __syncthreads();
    for (int off = 1; off < 256; off <<= 1) {
        int x = (t >= off) ? s[t - off] : 0;
        __syncthreads();
        if (t >= off) s[t] += x;
        __syncthreads();
    }
    int run = s[t] - sum;  // exclusive prefix of this thread's chunk
    if (t == 255) blockSums[b] = s[255];
#pragma unroll
    for (int i = 0; i < 4; i++) {
        if (base + i < SCAN_N) bins[base + i] = run;
        run += v[i];
    }
}

__global__ void scan2_kernel(int* __restrict__ blockSums, int nb) {
    __shared__ int s[256];
    int t = threadIdx.x;
    int carry = 0;
    for (int base = 0; base < nb; base += 256) {
        int v = (base + t < nb) ? blockSums[base + t] : 0;
        s[t] = v;
        __syncthreads();
        for (int off = 1; off < 256; off <<= 1) {
            int x = (t >= off) ? s[t - off] : 0;
            __syncthreads();
            if (t >= off) s[t] += x;
            __syncthreads();
        }
        if (base + t < nb) blockSums[base + t] = carry + (s[t] - v);
        int total = s[255];
        __syncthreads();
        carry += total;
    }
}

__global__ void scan3_kernel(int* __restrict__ bins, const int* __restrict__ blockSums,
                             int* __restrict__ binCur) {
    int i = blockIdx.x * 256 + threadIdx.x;
    if (i < SCAN_N) {
        int v = bins[i] + blockSums[i >> 10];
        bins[i] = v;
        binCur[i] = v;
    }
}

__global__ void scatter_kernel(const int* __restrict__ src, const int* __restrict__ dst,
                               const int* __restrict__ et, int* __restrict__ binCur,
                               int* __restrict__ srcSorted) {
    int e = blockIdx.x * 256 + threadIdx.x;
    if (e < NEDGE) {
        int bin = et[e] * NNODES + dst[e];
        int pos = atomicAdd(&binCur[bin], 1);
        srcSorted[pos] = src[e];
    }
}

// Build all relation/root weights directly into MFMA B-fragment layout,
// split into bf16 hi/lo pairs. One thread per matrix element.
// Segments: [0,65536) conv0 rels | [65536,131072) conv1 rels |
// [131072,147456) root1 | [147456,180224) conv2 rels | [180224,188416) root2
__global__ void fragify_kernel(const float* __restrict__ basis0, const float* __restrict__ comp0,
                               const float* __restrict__ basis1, const float* __restrict__ comp1,
                               const float* __restrict__ root1,
                               const float* __restrict__ basis2, const float* __restrict__ comp2,
                               const float* __restrict__ root2,
                               short* __restrict__ whi0, short* __restrict__ wlo0,
                               short* __restrict__ whi1, short* __restrict__ wlo1,
                               short* __restrict__ whiR1, short* __restrict__ wloR1,
                               short* __restrict__ whi2, short* __restrict__ wlo2,
                               short* __restrict__ whiR2, short* __restrict__ wloR2) {
    int idx = blockIdx.x * 256 + threadIdx.x;
    if (idx >= 188416) return;
    float w;
    short *hp, *lp;
    if (idx < 65536) {
        int r = idx >> 14, e = idx & 16383;
        int k = e >> 7, n = e & 127;
        w = 0.f;
#pragma unroll
        for (int b = 0; b < 4; b++) w += comp0[r * 4 + b] * basis0[b * 16384 + e];
        int off = r * 16384 + fragoff(k, n, 8);
        hp = whi0 + off; lp = wlo0 + off;
    } else if (idx < 131072) {
        int i2 = idx - 65536;
        int r = i2 >> 14, e = i2 & 16383;
        int k = e >> 7, n = e & 127;
        w = 0.f;
#pragma unroll
        for (int b = 0; b < 4; b++) w += comp1[r * 4 + b] * basis1[b * 16384 + e];
        int off = r * 16384 + fragoff(k, n, 8);
        hp = whi1 + off; lp = wlo1 + off;
    } else if (idx < 147456) {
        int e = idx - 131072;
        int k = e >> 7, n = e & 127;
        w = root1[e];
        int off = fragoff(k, n, 8);
        hp = whiR1 + off; lp = wloR1 + off;
    } else if (idx < 180224) {
        int i2 = idx - 147456;
        int r = i2 >> 13, e = i2 & 8191;
        int k = e >> 6, n = e & 63;
        w = 0.f;
#pragma unroll
        for (int b = 0; b < 4; b++) w += comp2[r * 4 + b] * basis2[b * 8192 + e];
        int off = r * 8192 + fragoff(k, n, 4);
        hp = whi2 + off; lp = wlo2 + off;
    } else {
        int e = idx - 180224;
        int k = e >> 6, n = e & 63;
        w = root2[e];
        int off = fragoff(k, n, 4);
        hp = whiR2 + off; lp = wloR2 + off;
    }
    unsigned short h = f2bf(w);
    unsigned short l = f2bf(w - bf2f(h));
    *hp = (short)h;
    *lp = (short)l;
}

// ---------------- projection GEMM: C[M,128] = relu(A[M,K] @ B[K,128] + bias) ----
__global__ __launch_bounds__(256) void gemm_kernel(const float* __restrict__ A,
                                                   const float* __restrict__ B,
                                                   const float* __restrict__ bias,
                                                   float* __restrict__ C, int M, int K) {
    __shared__ float sA[64 * 128];
    int tid = threadIdx.x;
    int row0 = blockIdx.x * 64;

    for (int i = tid; i < (64 * K) >> 2; i += 256) {
        int off = i << 2;
        int rr = off / K, cc = off % K;
        int row = row0 + rr;
        float4 v = {0.f, 0.f, 0.f, 0.f};
        if (row < M) v = *(const float4*)(A + (long)row * K + cc);
        *(float4*)(sA + rr * K + cc) = v;
    }
    __syncthreads();

    int cg = tid & 31, rg = tid >> 5;
    int c0 = cg * 4, r0 = rg * 8;
    float acc[8][4];
#pragma unroll
    for (int i = 0; i < 8; i++)
#pragma unroll
        for (int j = 0; j < 4; j++) acc[i][j] = 0.f;

#pragma unroll 2
    for (int k = 0; k < K; k += 4) {
        float a[8][4];
#pragma unroll
        for (int i = 0; i < 8; i++)
            *(float4*)(a[i]) = *(const float4*)(sA + (r0 + i) * K + k);
#pragma unroll
        for (int j = 0; j < 4; j++) {
            float b[4];
            *(float4*)b = *(const float4*)(B + (k + j) * 128 + c0);
#pragma unroll
            for (int i = 0; i < 8; i++)
#pragma unroll
                for (int jj = 0; jj < 4; jj++)
                    acc[i][jj] = fmaf(a[i][j], b[jj], acc[i][jj]);
        }
    }

#pragma unroll
    for (int i = 0; i < 8; i++) {
        int row = row0 + r0 + i;
        if (row >= M) continue;
        float v[4];
#pragma unroll
        for (int jj = 0; jj < 4; jj++) v[jj] = fmaxf(acc[i][jj] + bias[c0 + jj], 0.f);
        *(float4*)(C + (long)row * 128 + c0) = *(float4*)v;
    }
}

// ---------------- fused dst-centric RGCN conv, split-bf16 MFMA ----------------
// r0 skeleton (256 thr, 64 dst rows, interleaved gather->barrier->GEMM), but the
// per-phase GEMM is v_mfma_f32_16x16x32_bf16 with 3-term hi/lo split
// (ah*bh + al*bh + ah*bl ~ fp32 precision). Gather converts its fp32 means to
// bf16 hi/lo tiles at LDS-write time. Consumer per thread per phase:
// 32 ds_read_b128 + 16 global B-loads + 96 MFMA (vs ~1800 VALU-bound insts
// before). A/B share the same (group,elem)->k storage map, so the MFMA dot is
// layout-bijection-invariant; row/col/CD anchors are the HW-verified ones.
template <int NC, bool HASROOT, bool DORELU>
__global__ __launch_bounds__(256) void conv_kernel(const float* __restrict__ x,
                                                   const short* __restrict__ whiRel,
                                                   const short* __restrict__ wloRel,
                                                   const short* __restrict__ whiRoot,
                                                   const short* __restrict__ wloRoot,
                                                   const int* __restrict__ binStart,
                                                   const int* __restrict__ binEnd,
                                                   const int* __restrict__ srcSorted,
                                                   float* __restrict__ out) {
    constexpr int NB  = NC / 16;   // col tiles: 8 (NC=128) or 4 (NC=64)
    constexpr int KB  = HIDC / 32; // 4 K-chunks
    constexpr int TPW = NB / 4;    // col tiles per wave: 2 or 1
    __shared__ short sHi[64 * LDB];
    __shared__ short sLo[64 * LDB];
    int tid = threadIdx.x;
    int v0 = blockIdx.x * 64;

    const int grow = tid >> 2, gq = tid & 3;       // gather: 4 threads/row
    const int wave = tid >> 6, lane = tid & 63;    // mfma coords
    const int lrow = lane & 15, lgrp = lane >> 4;

    f32x4 acc[4][TPW];
#pragma unroll
    for (int rt = 0; rt < 4; rt++)
#pragma unroll
        for (int t = 0; t < TPW; t++) acc[rt][t] = (f32x4){0.f, 0.f, 0.f, 0.f};

    constexpr int NPHASE = HASROOT ? RELS + 1 : RELS;
#pragma unroll 1
    for (int ph = 0; ph < NPHASE; ph++) {
        if (ph > 0) __syncthreads();  // protect LDS from previous phase's readers
        if (ph < RELS) {
            int bin = ph * NNODES + v0 + grow;
            int s = binStart[bin], e = binEnd[bin];
            float4 a4[8];
#pragma unroll
            for (int i = 0; i < 8; i++) a4[i] = make_float4(0.f, 0.f, 0.f, 0.f);
            for (int j = s; j < e; j++) {
                const float* xs = x + (long)srcSorted[j] * HIDC;
#pragma unroll
                for (int i = 0; i < 8; i++) {
                    float4 v = *(const float4*)(xs + (gq + i * 4) * 4);
                    a4[i].x += v.x; a4[i].y += v.y; a4[i].z += v.z; a4[i].w += v.w;
                }
            }
            float sc = 1.0f / (float)max(e - s, 1);
#pragma unroll
            for (int i = 0; i < 8; i++) {
                float4 w = a4[i];
                w.x *= sc; w.y *= sc; w.z *= sc; w.w *= sc;
                unsigned short h0 = f2bf(w.x), h1 = f2bf(w.y), h2 = f2bf(w.z), h3 = f2bf(w.w);
                unsigned short l0 = f2bf(w.x - bf2f(h0)), l1 = f2bf(w.y - bf2f(h1));
                unsigned short l2 = f2bf(w.z - bf2f(h2)), l3 = f2bf(w.w - bf2f(h3));
                int c = (gq + i * 4) * 4;
                uint2 hv = make_uint2((unsigned)h0 | ((unsigned)h1 << 16),
                                      (unsigned)h2 | ((unsigned)h3 << 16));
                uint2 lv = make_uint2((unsigned)l0 | ((unsigned)l1 << 16),
                                      (unsigned)l2 | ((unsigned)l3 << 16));
                *(uint2*)(sHi + grow * LDB + c) = hv;
                *(uint2*)(sLo + grow * LDB + c) = lv;
            }
        } else {
            // root phase: coalesced load + convert of the block's own 64 x-rows
#pragma unroll
            for (int i = 0; i < 8; i++) {
                int i4 = tid + 256 * i;  // 2048 float4 = 64x128 floats
                int row = i4 >> 5, col4 = i4 & 31;
                float4 w = *(const float4*)(x + (long)(v0 + row) * HIDC + col4 * 4);
                unsigned short h0 = f2bf(w.x), h1 = f2bf(w.y), h2 = f2bf(w.z), h3 = f2bf(w.w);
                unsigned short l0 = f2bf(w.x - bf2f(h0)), l1 = f2bf(w.y - bf2f(h1));
                unsigned short l2 = f2bf(w.z - bf2f(h2)), l3 = f2bf(w.w - bf2f(h3));
                int c = col4 * 4;
                uint2 hv = make_uint2((unsigned)h0 | ((unsigned)h1 << 16),
                                      (unsigned)h2 | ((unsigned)h3 << 16));
                uint2 lv = make_uint2((unsigned)l0 | ((unsigned)l1 << 16),
                                      (unsigned)l2 | ((unsigned)l3 << 16));
                *(uint2*)(sHi + row * LDB + c) = hv;
                *(uint2*)(sLo + row * LDB + c) = lv;
            }
        }
        __syncthreads();

        const short* __restrict__ bhB = (ph < RELS) ? (whiRel + ph * (KB * NB * 512)) : whiRoot;
        const short* __restrict__ blB = (ph < RELS) ? (wloRel + ph * (KB * NB * 512)) : wloRoot;

#pragma unroll
        for (int kb = 0; kb < KB; kb++) {
            bf16x8 bh[TPW], bl[TPW];
#pragma unroll
            for (int t = 0; t < TPW; t++) {
                int nb = wave * TPW + t;
                int boff = ((kb * NB + nb) * 64 + lane) * 8;
                bh[t] = *(const bf16x8*)(bhB + boff);
                bl[t] = *(const bf16x8*)(blB + boff);
            }
#pragma unroll
            for (int rt = 0; rt < 4; rt++) {
                int aoff = (rt * 16 + lrow) * LDB + kb * 32 + lgrp * 8;
                bf16x8 ah = *(const bf16x8*)(sHi + aoff);
                bf16x8 al = *(const bf16x8*)(sLo + aoff);
#pragma unroll
                for (int t = 0; t < TPW; t++) {
                    acc[rt][t] = __builtin_amdgcn_mfma_f32_16x16x32_bf16(ah, bh[t], acc[rt][t], 0, 0, 0);
                    acc[rt][t] = __builtin_amdgcn_mfma_f32_16x16x32_bf16(al, bh[t], acc[rt][t], 0, 0, 0);
                    acc[rt][t] = __builtin_amdgcn_mfma_f32_16x16x32_bf16(ah, bl[t], acc[rt][t], 0, 0, 0);
                }
            }
        }
    }

    // epilogue: C/D layout col=lane&15, row=(lane>>4)*4+reg (HW-verified)
#pragma unroll
    for (int rt = 0; rt < 4; rt++)
#pragma unroll
        for (int t = 0; t < TPW; t++) {
            int nb = wave * TPW + t;
            int col = nb * 16 + lrow;
#pragma unroll
            for (int j = 0; j < 4; j++) {
                float vv = acc[rt][t][j];
                if (DORELU) vv = fmaxf(vv, 0.f);
                out[(long)(v0 + rt * 16 + lgrp * 4 + j) * NC + col] = vv;
            }
        }
}

// ---------------- launch ----------------

extern "C" void kernel_launch(void* const* d_in, const int* in_sizes, int n_in,
                              void* d_out, int out_size, void* d_ws, size_t ws_size,
                              hipStream_t stream) {
    const float* xa     = (const float*)d_in[0];
    const float* xp     = (const float*)d_in[1];
    const int*   src    = (const int*)d_in[2];
    const int*   dst    = (const int*)d_in[3];
    const int*   et     = (const int*)d_in[4];
    const float* Wpa    = (const float*)d_in[5];
    const float* bpa    = (const float*)d_in[6];
    const float* Wpb    = (const float*)d_in[7];
    const float* bpb    = (const float*)d_in[8];
    const float* basis0 = (const float*)d_in[9];
    const float* comp0  = (const float*)d_in[10];
    const float* basis1 = (const float*)d_in[11];
    const float* comp1  = (const float*)d_in[12];
    const float* root1  = (const float*)d_in[13];
    const float* basis2 = (const float*)d_in[14];
    const float* comp2  = (const float*)d_in[15];
    const float* root2  = (const float*)d_in[16];

    // d_out layout: final [N,64] | x_lat0 [N,128] | x_lat1 [N,128] | x_lat2 [N,128]
    float* out_final = (float*)d_out;
    float* x0 = out_final + (size_t)NNODES * OUTCH;
    float* x1 = x0 + (size_t)NNODES * HIDC;
    float* x2 = x1 + (size_t)NNODES * HIDC;

    // workspace (~9.56 MB)
    int* bins      = (int*)d_ws;            // 800000: counts -> starts
    int* binCur    = bins + SCAN_N;         // 800000: cursor -> ends
    int* blockSums = binCur + SCAN_N;       // 800
    int* srcSorted = blockSums + 800;       // 600000
    short* whi0  = (short*)(srcSorted + NEDGE);  // 4*4*8*512 = 65536
    short* wlo0  = whi0 + 65536;
    short* whi1  = wlo0 + 65536;                 // 65536
    short* wlo1  = whi1 + 65536;
    short* whiR1 = wlo1 + 65536;                 // 16384
    short* wloR1 = whiR1 + 16384;
    short* whi2  = wloR1 + 16384;                // 32768
    short* wlo2  = whi2 + 32768;
    short* whiR2 = wlo2 + 32768;                 // 8192
    short* wloR2 = whiR2 + 8192;

    dim3 b256(256);
    int egrid = (NEDGE + 255) / 256;
    int nScanBlocks = (SCAN_N + 1023) / 1024;  // 782

    // ---- counting-sort of src ids by (relation, dst) ----
    hipMemsetAsync(bins, 0, (size_t)SCAN_N * sizeof(int), stream);
    hipLaunchKernelGGL(count_kernel, dim3(egrid), b256, 0, stream, dst, et, bins);
    hipLaunchKernelGGL(scan1_kernel, dim3(nScanBlocks), b256, 0, stream, bins, blockSums);
    hipLaunchKernelGGL(scan2_kernel, dim3(1), b256, 0, stream, blockSums, nScanBlocks);
    hipLaunchKernelGGL(scan3_kernel, dim3((SCAN_N + 255) / 256), b256, 0, stream,
                       bins, blockSums, binCur);
    hipLaunchKernelGGL(scatter_kernel, dim3(egrid), b256, 0, stream,
                       src, dst, et, binCur, srcSorted);

    // ---- materialize relation+root weights as bf16 hi/lo MFMA fragments ----
    hipLaunchKernelGGL(fragify_kernel, dim3((188416 + 255) / 256), b256, 0, stream,
                       basis0, comp0, basis1, comp1, root1, basis2, comp2, root2,
                       whi0, wlo0, whi1, wlo1, whiR1, wloR1, whi2, wlo2, whiR2, wloR2);

    // ---- projections -> x_lat0 ----
    hipLaunchKernelGGL(gemm_kernel, dim3((NAUT + 63) / 64), b256, 0, stream,
                       xa, Wpa, bpa, x0, NAUT, 64);
    hipLaunchKernelGGL(gemm_kernel, dim3((NAUT + 63) / 64), b256, 0, stream,
                       xp, Wpb, bpb, x0 + (size_t)NAUT * HIDC, NAUT, 96);

    int cgrid = NNODES / 64;  // 3125, exact

    // conv0: x1 = relu(aggr(x0))            (no root)
    hipLaunchKernelGGL((conv_kernel<128, false, true>), dim3(cgrid), b256, 0, stream,
                       x0, whi0, wlo0, (const short*)nullptr, (const short*)nullptr,
                       bins, binCur, srcSorted, x1);
    // conv1: x2 = relu(x1 @ root1 + aggr(x1))
    hipLaunchKernelGGL((conv_kernel<128, true, true>), dim3(cgrid), b256, 0, stream,
                       x1, whi1, wlo1, whiR1, wloR1, bins, binCur, srcSorted, x2);
    // conv2: final = x2 @ root2 + aggr(x2)  (no relu)
    hipLaunchKernelGGL((conv_kernel<64, true, false>), dim3(cgrid), b256, 0, stream,
                       x2, whi2, wlo2, whiR2, wloR2, bins, binCur, srcSorted, out_final);
}